// Round 1
// baseline (1397.721 us; speedup 1.0000x reference)
//
#include <hip/hip_runtime.h>
#include <hip/hip_bf16.h>

// Problem constants
#define IN_DIM 256          // S*F = 32*8
#define TRI    32896        // (256 + 256^2)/2
#define FEAT   33152        // IN_DIM + TRI
#define F4     8288         // FEAT/4
#define NROWS  8192         // NHEAD * S * D_MODEL = 4*2048
#define BATCH  8
#define S      32
#define DM     64
#define OUTF   64

// ---------------- Kernel 1: build feats[b][FEAT] ----------------
// feats[b][0:256]   = x_flat[b]
// feats[b][256 + t] = x[b][i]*x[b][j], t enumerates triu (i,j) row-major
__global__ __launch_bounds__(256) void feats_kernel(
    const float* __restrict__ x, float* __restrict__ feats) {
  const int i = blockIdx.x;   // 0..255
  const int b = blockIdx.y;   // 0..7
  const int j = threadIdx.x;  // 0..255
  __shared__ float xb[IN_DIM];
  xb[j] = x[b * IN_DIM + j];
  __syncthreads();
  float* fb = feats + (size_t)b * FEAT;
  if (i == 0) fb[j] = xb[j];
  if (j >= i) {
    int t = i * IN_DIM - (i * (i - 1)) / 2 + (j - i);
    fb[IN_DIM + t] = xb[i] * xb[j];
  }
}

// ---------------- Kernel 2: head_out[b][r] = feats[b] . W[r] + bias[r] -----
// Grid: NROWS/4 blocks of 256 threads. Each block: 4 consecutive rows.
// Each thread: acc[4 rows][8 batches], strided float4 loads of W (coalesced,
// HBM-streamed) and feats (L2-resident, reused across 4 rows in registers).
__global__ __launch_bounds__(256) void head_gemv(
    const float* __restrict__ W, const float* __restrict__ feats,
    const float* __restrict__ bias, float* __restrict__ head_out) {
  const int tid = threadIdx.x;
  const int r0  = blockIdx.x * 4;
  const float4* __restrict__ Wf4 = (const float4*)W;
  const float4* __restrict__ Ff4 = (const float4*)feats;

  float acc[4][8];
#pragma unroll
  for (int r = 0; r < 4; ++r)
#pragma unroll
    for (int b = 0; b < 8; ++b) acc[r][b] = 0.f;

  for (int k4 = tid; k4 < F4; k4 += 256) {
    float4 f[8];
#pragma unroll
    for (int b = 0; b < 8; ++b) f[b] = Ff4[(size_t)b * F4 + k4];
#pragma unroll
    for (int r = 0; r < 4; ++r) {
      float4 w = Wf4[(size_t)(r0 + r) * F4 + k4];
#pragma unroll
      for (int b = 0; b < 8; ++b)
        acc[r][b] += w.x * f[b].x + w.y * f[b].y + w.z * f[b].z + w.w * f[b].w;
    }
  }

  // Wave-level shuffle reduction (wave = 64 lanes on gfx950)
#pragma unroll
  for (int r = 0; r < 4; ++r)
#pragma unroll
    for (int b = 0; b < 8; ++b)
#pragma unroll
      for (int off = 32; off > 0; off >>= 1)
        acc[r][b] += __shfl_down(acc[r][b], off, 64);

  __shared__ float red[4][32];
  const int wave = tid >> 6;
  const int lane = tid & 63;
  if (lane == 0) {
#pragma unroll
    for (int r = 0; r < 4; ++r)
#pragma unroll
      for (int b = 0; b < 8; ++b) red[wave][r * 8 + b] = acc[r][b];
  }
  __syncthreads();
  if (tid < 32) {
    float v = red[0][tid] + red[1][tid] + red[2][tid] + red[3][tid];
    const int r = tid >> 3;  // 0..3
    const int b = tid & 7;   // 0..7
    head_out[(size_t)b * NROWS + r0 + r] = v + bias[r0 + r];
  }
}

// ---------------- Kernel 3: out[b][s][of] = concat[b][s] . W_out[of] + b_out
// concat[b][s][h*64+dm] = head_out[b][h*2048 + s*64 + dm]
__global__ __launch_bounds__(64) void out_kernel(
    const float* __restrict__ head_out, const float* __restrict__ W_out,
    const float* __restrict__ b_out, float* __restrict__ out) {
  const int bs = blockIdx.x;  // b*32 + s
  const int b  = bs >> 5;
  const int s  = bs & 31;
  const int of = threadIdx.x;  // 0..63
  __shared__ float c[256];
#pragma unroll
  for (int i = 0; i < 4; ++i) {
    int idx = of + i * 64;
    int h = idx >> 6, dm = idx & 63;
    c[idx] = head_out[(size_t)b * NROWS + h * (S * DM) + s * DM + dm];
  }
  __syncthreads();
  float acc = b_out[of];
  const float4* __restrict__ wr = (const float4*)(W_out + of * 256);
  const float4* __restrict__ cc = (const float4*)c;
#pragma unroll 8
  for (int q = 0; q < 64; ++q) {
    float4 w = wr[q];
    float4 v = cc[q];  // broadcast across lanes: conflict-free
    acc += w.x * v.x + w.y * v.y + w.z * v.z + w.w * v.w;
  }
  out[bs * OUTF + of] = acc;
}

extern "C" void kernel_launch(void* const* d_in, const int* in_sizes, int n_in,
                              void* d_out, int out_size, void* d_ws, size_t ws_size,
                              hipStream_t stream) {
  const float* input_  = (const float*)d_in[0];  // (8, 32, 8)
  const float* W_heads = (const float*)d_in[1];  // (4, 2048, 33152)
  const float* b_heads = (const float*)d_in[2];  // (4, 2048)
  const float* W_out   = (const float*)d_in[3];  // (64, 256)
  const float* b_out   = (const float*)d_in[4];  // (64,)
  float* out = (float*)d_out;                    // (8, 32, 64)

  // Workspace layout
  float* feats    = (float*)d_ws;                       // 8*33152 floats
  float* head_out = feats + (size_t)BATCH * FEAT;       // 8*8192 floats

  feats_kernel<<<dim3(IN_DIM, BATCH), 256, 0, stream>>>(input_, feats);
  head_gemv<<<NROWS / 4, 256, 0, stream>>>(W_heads, feats, b_heads, head_out);
  out_kernel<<<BATCH * S, 64, 0, stream>>>(head_out, W_out, b_out, out);
}